// Round 11
// baseline (262.378 us; speedup 1.0000x reference)
//
#include <hip/hip_runtime.h>
#include <math.h>

// SSIM loss, round 11: r5 math, 256-thread blocks for cross-block latency hiding.
// Algebra: s=x+y, d=x-y; 4 separable Gaussian convs (s, d, s^2, d^2):
//   2*mu1mu2 = (mp^2-mm^2)/2 ; mu1^2+mu2^2 = (mp^2+mm^2)/2
//   2*s12    = (varP-varM)/2 ; s11+s22    = (varP+varM)/2
// Evidence (r1..r10): 256-thr blocks reach their occupancy ceiling (r10),
// 512-thr blocks never exceed ~1 resident block (r1/r3/r4/r5) -> barrier
// lockstep + memory latency exposed -> VALUBusy pinned ~47%. This round:
// 256-thr blocks, 256-col strips, 17.4KB LDS -> >=4 blocks/CU, phase-mixed.
// Col halo (5 each side) for the horizontal pass is computed redundantly by
// wave 0 (lanes<10) as a direct 14-row x 11-tap conv with transient 16-reg
// accumulators; halo loads issued before the main vertical rows so ~400cy of
// ring FMAs cover their latency. Image-edge halos = zeros via clamp+select.

#define HH 512
#define WW 512
#define CH 4         // chunk rows per barrier period
#define NCHUNK 16
#define NSLOT 272    // V slots per row: 266 used (5 halo + 256 + 5 halo) + pad
#define NT 256

#define C1F 0.0001f  // 0.01^2
#define C2F 0.0009f  // 0.03^2

typedef float f32x4 __attribute__((ext_vector_type(4)));

// XOR swizzle, bijective on [0,272): toggles low 3 bits by bits 5..7
__device__ __forceinline__ int swz(int s) { return s ^ ((s >> 5) & 7); }

extern "C" __global__ __launch_bounds__(NT)
void ssim_main(const float* __restrict__ Ii, const float* __restrict__ Ir,
               const float* __restrict__ win, float* __restrict__ partial) {
  __shared__ f32x4 vbuf[CH * NSLOT];   // 4*272*16 = 17408 B
  __shared__ float psum[4];

  const int tid = threadIdx.x;
  const int b = blockIdx.x;
  const int plane = b >> 4;            // 96 planes
  const int band = (b >> 1) & 7;       // 8 row bands of 64
  const int chs = b & 1;               // 2 col strips of 256
  const int r0 = band * 64;
  const int cb = chs * 256;

  // 1-D gaussian from the 2-D window (wave-uniform)
  float g[11];
  {
    const float gi = 1.0f / sqrtf(win[55 + 5]);
#pragma unroll
    for (int j = 0; j < 11; ++j) g[j] = win[55 + j] * gi;
  }

  const int w = tid >> 6;
  const int lane = tid & 63;
  const int mycol = cb + tid;          // this thread's column (always in-image)
  const int pb = plane * (HH * WW);
  const int wslot = swz(tid + 5);      // own V slot (local col = tid+5)

  // halo ownership: wave 0, lanes 0..9
  const int hcol = (lane < 5) ? (cb - 5 + lane) : (cb + 251 + lane); // may be OOB
  const bool hcolok = (unsigned)hcol < (unsigned)WW;
  const int hcc = min(max(hcol, 0), WW - 1);
  const int hslot = swz((lane < 5) ? lane : (256 + lane));           // 0..4 / 261..265

  // mod-11 ring accumulators (fully unrolled -> static indices)
  float rS[11], rD[11], rP[11], rM[11];
  float pfA[CH], pfB[CH];              // main-col prefetch
  float haA[14], haB[14];              // halo row staging (wave 0 only, transient)
  float sum = 0.f;

  auto loadrow = [&](int u, float& a, float& bb) {
    const int r = r0 - 5 + u;
    const int rc = min(max(r, 0), HH - 1);
    const int off = pb + rc * WW + mycol;
    float ta = Ii[off];
    float tb = Ir[off];
    const bool ok = (unsigned)r < (unsigned)HH;
    a = ok ? ta : 0.f;
    bb = ok ? tb : 0.f;
  };

  // vertical ring step for input local row u; emit output local row lr when >=0
  auto vrow = [&](int u, float a, float bb, int lr) {
    const float s = a + bb, d = a - bb;
    const float p = s * s, m = d * d;
    {
      const int sl = u % 11;
      rS[sl] = g[0] * s; rD[sl] = g[0] * d;
      rP[sl] = g[0] * p; rM[sl] = g[0] * m;
    }
#pragma unroll
    for (int t = 1; t < 11; ++t) {
      const int sl = (u + 44 - t) % 11;
      rS[sl] = fmaf(g[t], s, rS[sl]);
      rD[sl] = fmaf(g[t], d, rD[sl]);
      rP[sl] = fmaf(g[t], p, rP[sl]);
      rM[sl] = fmaf(g[t], m, rM[sl]);
    }
    if (lr >= 0) {
      const int sl = (u + 1) % 11;     // (u-10) mod 11
      f32x4 o; o.x = rS[sl]; o.y = rD[sl]; o.z = rP[sl]; o.w = rM[sl];
      vbuf[lr * NSLOT + wslot] = o;
    }
  };

  // horizontal conv + SSIM for the CH rows in LDS; thread: row=w, 4 px
  auto hchunk = [&]() {
    float h0[4], h1[4], h2[4], h3[4];
    const int rb = w * NSLOT;
    const int jg = lane * 4;           // local col of first px
#pragma unroll
    for (int k = 0; k < 14; ++k) {
      const f32x4 v = vbuf[rb + swz(jg + k)];
      const int clo = (k - 10 > 0) ? (k - 10) : 0;
      const int chi = (k < 3) ? k : 3;
#pragma unroll
      for (int c = clo; c <= chi; ++c) {
        const float wt = g[k - c];
        if (c == k) { h0[c] = wt * v.x; h1[c] = wt * v.y; h2[c] = wt * v.z; h3[c] = wt * v.w; }
        else {
          h0[c] = fmaf(wt, v.x, h0[c]);
          h1[c] = fmaf(wt, v.y, h1[c]);
          h2[c] = fmaf(wt, v.z, h2[c]);
          h3[c] = fmaf(wt, v.w, h3[c]);
        }
      }
    }
#pragma unroll
    for (int c = 0; c < 4; ++c) {
      const float mp2 = h0[c] * h0[c];
      const float mm2 = h1[c] * h1[c];
      const float varP = h2[c] - mp2;
      const float varM = h3[c] - mm2;
      const float num1 = 0.5f * (mp2 - mm2) + C1F;
      const float den1 = 0.5f * (mp2 + mm2) + C1F;
      const float num2 = 0.5f * (varP - varM) + C2F;
      const float den2 = 0.5f * (varP + varM) + C2F;
      sum += __fdividef(num1 * num2, den1 * den2);
    }
  };

  // prologue: ring fill (u=0..9), prefetch chunk 0 (u=10..13)
#pragma unroll
  for (int u = 0; u < 10; ++u) {
    float a, bb; loadrow(u, a, bb); vrow(u, a, bb, -1);
  }
#pragma unroll
  for (int i = 0; i < CH; ++i) loadrow(10 + i, pfA[i], pfB[i]);

  for (int c = 0; c < NCHUNK; ++c) {
    // (1) wave 0: issue this chunk's 28 halo loads (latency covered by (2))
    if (w == 0 && lane < 10) {
#pragma unroll
      for (int u2 = 0; u2 < 14; ++u2) {
        const int gr = r0 + 4 * c - 5 + u2;
        const int grc = min(max(gr, 0), HH - 1);
        const int off = pb + grc * WW + hcc;
        haA[u2] = Ii[off];
        haB[u2] = Ir[off];
      }
    }
    // (2) main vertical: consume prefetched rows, write V rows 0..3
#pragma unroll
    for (int i = 0; i < CH; ++i) vrow(10 + 4 * c + i, pfA[i], pfB[i], i);
    // (3) issue next chunk's main prefetch (in flight across barriers)
    if (c < NCHUNK - 1) {
#pragma unroll
      for (int i = 0; i < CH; ++i) loadrow(14 + 4 * c + i, pfA[i], pfB[i]);
    }
    // (4) wave 0: direct 11-tap vertical conv for the 10 halo cols
    if (w == 0 && lane < 10) {
      float aS[4], aD[4], aP[4], aM[4];
#pragma unroll
      for (int j = 0; j < 4; ++j) { aS[j] = 0.f; aD[j] = 0.f; aP[j] = 0.f; aM[j] = 0.f; }
#pragma unroll
      for (int u2 = 0; u2 < 14; ++u2) {
        const int gr = r0 + 4 * c - 5 + u2;
        const bool ok = hcolok && ((unsigned)gr < (unsigned)HH);
        const float a = ok ? haA[u2] : 0.f;
        const float bb = ok ? haB[u2] : 0.f;
        const float s = a + bb, d = a - bb;
        const float p = s * s, m = d * d;
        const int jlo = (u2 - 10 > 0) ? (u2 - 10) : 0;
        const int jhi = (u2 < 3) ? u2 : 3;
#pragma unroll
        for (int j = jlo; j <= jhi; ++j) {
          const float wt = g[u2 - j];
          aS[j] = fmaf(wt, s, aS[j]);
          aD[j] = fmaf(wt, d, aD[j]);
          aP[j] = fmaf(wt, p, aP[j]);
          aM[j] = fmaf(wt, m, aM[j]);
        }
      }
#pragma unroll
      for (int j = 0; j < 4; ++j) {
        f32x4 o; o.x = aS[j]; o.y = aD[j]; o.z = aP[j]; o.w = aM[j];
        vbuf[j * NSLOT + hslot] = o;
      }
    }
    asm volatile("s_waitcnt lgkmcnt(0)" ::: "memory");  // V writes visible
    __builtin_amdgcn_s_barrier();
    hchunk();
    if (c < NCHUNK - 1) {
      asm volatile("s_waitcnt lgkmcnt(0)" ::: "memory"); // V reads done
      __builtin_amdgcn_s_barrier();                      // before next V writes
    }
  }

  // deterministic block reduction
#pragma unroll
  for (int off = 32; off > 0; off >>= 1) sum += __shfl_down(sum, off, 64);
  if (lane == 0) psum[w] = sum;
  __syncthreads();
  if (tid == 0) partial[b] = psum[0] + psum[1] + psum[2] + psum[3];
}

extern "C" __global__ void ssim_reduce(const float* __restrict__ partial,
                                       float* __restrict__ out, int n, float scale) {
  __shared__ float sm[4];
  const int tid = threadIdx.x;
  float v = 0.f;
  for (int i = tid; i < n; i += 256) v += partial[i];
#pragma unroll
  for (int off = 32; off > 0; off >>= 1) v += __shfl_down(v, off, 64);
  if ((tid & 63) == 0) sm[tid >> 6] = v;
  __syncthreads();
  if (tid == 0) {
    out[0] = 1.0f - (sm[0] + sm[1] + sm[2] + sm[3]) * scale;
  }
}

extern "C" void kernel_launch(void* const* d_in, const int* in_sizes, int n_in,
                              void* d_out, int out_size, void* d_ws, size_t ws_size,
                              hipStream_t stream) {
  const float* Ii = (const float*)d_in[0];
  const float* Ir = (const float*)d_in[1];
  const float* win = (const float*)d_in[2];
  float* out = (float*)d_out;
  float* partial = (float*)d_ws;   // 1536 floats

  const int nblocks = 96 * 8 * 2;  // plane x band x col-strip = 1536
  ssim_main<<<dim3(nblocks), dim3(NT), 0, stream>>>(Ii, Ir, win, partial);
  ssim_reduce<<<dim3(1), dim3(256), 0, stream>>>(partial, out, nblocks,
                                                 1.0f / 25165824.0f);
}